// Round 7
// baseline (109.340 us; speedup 1.0000x reference)
//
#include <hip/hip_runtime.h>
#include <math.h>

// Problem dims (fixed by setup_inputs): B=2, D=64, H=96, W=96, fp32.
#define BDIM 2
#define DDIM 64
#define HDIM 96
#define WDIM 96
#define HW   (HDIM * WDIM)
#define DHW  (DDIM * HW)

// Window optimization (validated R5/R6, absmax 0.0): capping squared distances
// at 25 preserves the loss weight BIT-EXACTLY, so the capped 3D EDT is local
// (+-4 halo per axis) and fully fusable.
//
// R6 post-mortem fixes: 576 blocks (8d x 8h x 32w interior, 26 KB LDS -> ~9
// waves/CU), ballot-based bitpack (no LDS atomics / int division), and packed
// uchar4-in-u32 min-plus taps (ds_read_b32 + branchless SIMD byte-min instead
// of byte-granular LDS traffic).
#define DT 8
#define HT 8
#define WT 32
#define DH 16            // DT + 8
#define HH 16            // HT + 8
#define NROWS (DH * HH)  // 256 (d,h) rows of 40 mask bits
#define NBLK  (BDIM * (DDIM / DT) * (HDIM / HT) * (WDIM / WT))  // 576

// ---------------------------------------------------------------------------
// Kernel 1: zero the accumulators + completion counter (ws is poisoned 0xAA).
// ---------------------------------------------------------------------------
__global__ void init_acc(float* __restrict__ acc) {
    if (threadIdx.x < 4) acc[threadIdx.x] = 0.0f;
    if (threadIdx.x == 4) ((int*)acc)[4] = 0;
}

// nearest set bit in a 9-bit window (center = bit 4) -> squared distance,
// 25 if none. Masks: d=0:0x010 d=1:0x028 d=2:0x044 d=3:0x082 d=4:0x101.
__device__ __forceinline__ unsigned nearest2i(unsigned occ) {
    unsigned r = 25u;
    if (occ & 0x101u) r = 16u;
    if (occ & 0x082u) r = 9u;
    if (occ & 0x044u) r = 4u;
    if (occ & 0x028u) r = 1u;
    if (occ & 0x010u) r = 0u;
    return r;
}

// per-byte unsigned min of 4 packed uint8 (requires all bytes <= 127).
// c flags bytes where a >= b; mask = 0xFF per flagged byte (no cross-byte
// borrows since byte values of (a|0x80)-b stay in [1,255]).
__device__ __forceinline__ unsigned vminu4(unsigned a, unsigned b) {
    unsigned c = ((a | 0x80808080u) - b) & 0x80808080u;
    unsigned m = (c - (c >> 7)) | c;     // 0x80 -> 0xFF, 0 -> 0
    return a ^ ((a ^ b) & m);            // m=FF -> b, m=0 -> a
}

// ---------------------------------------------------------------------------
// Kernel 2: fully fused boundary loss. grid = 576 blocks x 256 threads.
// Stages: ballot bitpack -> W pass (bits -> packed uchar4) -> H pass (packed
// 9-tap int min-plus) -> D pass + loss + reduction -> last-block finalize.
// ---------------------------------------------------------------------------
__global__ __launch_bounds__(256) void boundary_fused(const float* __restrict__ pred,
                                                      const float* __restrict__ target,
                                                      float* __restrict__ acc,
                                                      float* __restrict__ out) {
    __shared__ unsigned long long fgb[NROWS];          // fg mask bits per (d,h) row
    __shared__ unsigned swp[NROWS * 8];                // W-pass dist2 to bg, uchar4
    __shared__ unsigned swn[NROWS * 8];                // W-pass dist2 to fg, uchar4
    __shared__ unsigned whp[DH * HT * 8];              // W+H dist2 to bg, uchar4
    __shared__ unsigned whn[DH * HT * 8];              // W+H dist2 to fg, uchar4
    __shared__ float rsum[8];

    const int tid = threadIdx.x;
    int x = blockIdx.x;
    const int wt = x % 3;  x /= 3;
    const int ht = x % 12; x /= 12;
    const int dt = x % 8;
    const int b  = x / 8;
    const int d0 = dt * DT, h0 = ht * HT, w0 = wt * WT;

    // valid-bit pattern for the 40-bit w-window (volume edges), per block
    unsigned long long vb_row = (1ULL << 40) - 1;
    if (wt == 0) vb_row &= ~0xFULL;                    // w = -4..-1 invalid
    if (wt == 2) vb_row &= (1ULL << 36) - 1;           // w = 96..99 invalid

    // ---- stage 1: bitpack via ballot; each wave packs one row per iter ----
    {
        const int lane = tid & 63;
        const int wv   = tid >> 6;                     // wave 0..3
        #pragma unroll 4
        for (int i = 0; i < 64; ++i) {
            const int row = wv * 64 + i;
            const int dr = row >> 4, hr = row & 15;
            const int d = d0 - 4 + dr, h = h0 - 4 + hr, w = w0 - 4 + lane;
            const bool valid = (lane < 40) && ((unsigned)d < DDIM) &&
                               ((unsigned)h < HDIM) && ((unsigned)w < WDIM);
            float v = 0.0f;
            if (valid) v = target[((size_t)(b * DDIM + d) * HDIM + h) * WDIM + w];
            unsigned long long bb = __ballot(v > 0.5f);
            if (lane == 0) fgb[row] = bb;
        }
    }
    __syncthreads();

    // ---- stage 2: W pass, bits -> packed capped dist2 ----
    {
        const int q  = tid & 7;                        // uchar4 group (w 4q..4q+3)
        const int rg = tid >> 3;                       // 0..31
        #pragma unroll
        for (int k = 0; k < 8; ++k) {
            const int row = rg + 32 * k;
            const int dr = row >> 4, hr = row & 15;
            const bool rv = ((unsigned)(d0 - 4 + dr) < DDIM) &&
                            ((unsigned)(h0 - 4 + hr) < HDIM);
            const unsigned long long fg = fgb[row];
            const unsigned long long vb = rv ? vb_row : 0ULL;
            unsigned pa = 0u, na = 0u;
            #pragma unroll
            for (int j = 0; j < 4; ++j) {
                const int wi = q * 4 + j;              // bits wi..wi+8 = w-4..w+4
                const unsigned of = (unsigned)(fg >> wi) & 0x1FFu;
                const unsigned ov = (unsigned)(vb >> wi) & 0x1FFu;
                const unsigned ob = ~of & ov;
                na |= nearest2i(of) << (8 * j);        // dist2 to nearest fg
                pa |= nearest2i(ob) << (8 * j);        // dist2 to nearest bg
            }
            swp[row * 8 + q] = pa;
            swn[row * 8 + q] = na;
        }
    }
    __syncthreads();

    // ---- stage 3: H pass, packed 9-tap min-plus ----
    #pragma unroll
    for (int k = 0; k < 4; ++k) {
        const int g  = tid + 256 * k;                  // (dr 0..15, hh 0..7, q 0..7)
        const int q  = g & 7;
        const int hh = (g >> 3) & 7;
        const int dr = g >> 6;
        unsigned p = 0x19191919u, n = 0x19191919u;     // 25 per byte
        #pragma unroll
        for (int t = 0; t < 9; ++t) {
            const int dd = (t - 4) * (t - 4);
            const unsigned add = (unsigned)dd * 0x01010101u;
            const int src = (dr * HH + hh + t) * 8 + q;
            p = vminu4(p, swp[src] + add);             // bytes <= 41 < 128: exact
            n = vminu4(n, swn[src] + add);
        }
        whp[(dr * HT + hh) * 8 + q] = p;
        whn[(dr * HT + hh) * 8 + q] = n;
    }
    __syncthreads();

    // ---- stage 4: D pass + loss on interior 8d x 8h x 32w ----
    float num = 0.f, den = 0.f;
    #pragma unroll
    for (int k = 0; k < 2; ++k) {
        const int g  = tid + 256 * k;                  // (di 0..7, hh 0..7, q 0..7)
        const int q  = g & 7;
        const int hh = (g >> 3) & 7;
        const int di = g >> 6;
        unsigned p = 0x19191919u, n = 0x19191919u;
        #pragma unroll
        for (int t = 0; t < 9; ++t) {
            const int dd = (t - 4) * (t - 4);
            const unsigned add = (unsigned)dd * 0x01010101u;
            const int src = ((di + t) * HT + hh) * 8 + q;
            p = vminu4(p, whp[src] + add);
            n = vminu4(n, whn[src] + add);
        }
        const size_t gg = ((size_t)(b * DDIM + d0 + di) * HDIM + h0 + hh) * WDIM
                        + w0 + q * 4;
        const float4 pr = *(const float4*)(pred + gg);
        const float4 tg = *(const float4*)(target + gg);
        #pragma unroll
        for (int j = 0; j < 4; ++j) {
            const float pv = (float)((p >> (8 * j)) & 0xFFu);
            const float nv = (float)((n >> (8 * j)) & 0xFFu);
            const float prj = j == 0 ? pr.x : j == 1 ? pr.y : j == 2 ? pr.z : pr.w;
            const float tgj = j == 0 ? tg.x : j == 1 ? tg.y : j == 2 ? tg.z : tg.w;
            const float dp = sqrtf(pv);
            const float dn = sqrtf(nv);
            const float a  = fabsf(dn - dp);
            float w;
            if (a <= 3.0f)      w = 1.0f;
            else if (a >= 5.0f) w = 0.0f;
            else                w = 1.0f - (a - 3.0f) * 0.5f;
            const float lp  = fmaxf(logf(prj), -100.0f);
            const float l1  = fmaxf(logf(1.0f - prj), -100.0f);
            const float bce = -(tgj * lp + (1.0f - tgj) * l1);
            num += bce * w;
            den += w;
        }
    }

    // ---- wave reduce -> cross-wave LDS -> one atomic pair per block ----
    for (int off = 32; off > 0; off >>= 1) {
        num += __shfl_down(num, off);
        den += __shfl_down(den, off);
    }
    if ((tid & 63) == 0) {
        rsum[tid >> 6]       = num;
        rsum[4 + (tid >> 6)] = den;
    }
    __syncthreads();
    if (tid == 0) {
        float ns = rsum[0] + rsum[1] + rsum[2] + rsum[3];
        float ds = rsum[4] + rsum[5] + rsum[6] + rsum[7];
        atomicAdd(&acc[b], ns);
        atomicAdd(&acc[2 + b], ds);
        __threadfence();
        int done = atomicAdd((int*)acc + 4, 1);
        if (done == NBLK - 1) {                        // last block: finalize
            __threadfence();
            float n0  = atomicAdd(&acc[0], 0.0f);
            float n1  = atomicAdd(&acc[1], 0.0f);
            float d0_ = atomicAdd(&acc[2], 0.0f);
            float d1_ = atomicAdd(&acc[3], 0.0f);
            out[0] = 0.5f * (n0 / (d0_ + 1e-5f) + n1 / (d1_ + 1e-5f));
        }
    }
}

extern "C" void kernel_launch(void* const* d_in, const int* in_sizes, int n_in,
                              void* d_out, int out_size, void* d_ws, size_t ws_size,
                              hipStream_t stream) {
    const float* pred   = (const float*)d_in[0];
    const float* target = (const float*)d_in[1];
    float* acc = (float*)d_ws;          // 4 floats num/den + 1 int counter
    float* out = (float*)d_out;

    init_acc<<<1, 64, 0, stream>>>(acc);
    boundary_fused<<<NBLK, 256, 0, stream>>>(pred, target, acc, out);
}

// Round 8
// 94.662 us; speedup vs baseline: 1.1551x; 1.1551x over previous
//
#include <hip/hip_runtime.h>
#include <math.h>

// Problem dims (fixed by setup_inputs): B=2, D=64, H=96, W=96, fp32.
#define BDIM 2
#define DDIM 64
#define HDIM 96
#define WDIM 96

// Window optimization (validated R5-R7, absmax 0.0): capping squared distances
// at 25 preserves the loss weight BIT-EXACTLY, so the capped 3D EDT is local
// (+-4 halo per axis) and fully fusable.
//
// R7 post-mortem: ballot bitpack serialized 64 dependent load+ballot rounds
// per wave -> unhidden HBM latency. R8: byte-mask staging with 10 independent
// float4 loads/thread (max MLP), W-pass via byte-shifted windows on the mask
// (dist = 25 - m*(25-d2), exact per packed byte), whp/whn aliased onto the
// dead mask arrays (36 KB LDS -> 4 blocks/CU, grid fully co-resident).
#define DT 8
#define HT 8
#define WT 32
#define DH 16            // DT + 8
#define HH 16            // HT + 8
#define NROWS (DH * HH)  // 256 (d,h) rows; each row = 40 mask bytes = 10 u32
#define NBLK  (BDIM * (DDIM / DT) * (HDIM / HT) * (WDIM / WT))  // 576

// ---------------------------------------------------------------------------
// Kernel 1: zero the accumulators + completion counter (ws is poisoned 0xAA).
// ---------------------------------------------------------------------------
__global__ void init_acc(float* __restrict__ acc) {
    if (threadIdx.x < 4) acc[threadIdx.x] = 0.0f;
    if (threadIdx.x == 4) ((int*)acc)[4] = 0;
}

// per-byte unsigned min of 4 packed uint8 (requires all bytes <= 127).
__device__ __forceinline__ unsigned vminu4(unsigned a, unsigned b) {
    unsigned c = ((a | 0x80808080u) - b) & 0x80808080u;
    unsigned m = (c - (c >> 7)) | c;     // 0x80 -> 0xFF, 0 -> 0
    return a ^ ((a ^ b) & m);            // m=FF -> b, m=0 -> a
}

// bytes t..t+3 of the 12-byte window {W0,W1,W2} (little-endian byte order)
__device__ __forceinline__ unsigned shiftw(unsigned lo, unsigned hi, int t) {
#if __has_builtin(__builtin_amdgcn_alignbyte)
    return __builtin_amdgcn_alignbyte(hi, lo, t);   // ({hi,lo} >> 8t)
#else
    return (lo >> (8 * t)) | (hi << (32 - 8 * t));
#endif
}

// W-pass for one packed quad: mask words W0..W2 (bytes 0/1), returns capped
// dist2 (<=25) per byte. Uses t/(8-t) symmetry: pair taps share 25-d2.
__device__ __forceinline__ unsigned wpass_quad(unsigned W0, unsigned W1, unsigned W2) {
    unsigned m = 0x19191919u - W1 * 25u;                 // t=4 (d=0), k=25
    unsigned u08 = W0 | W2;                              // d=+-4, k=9
    m = vminu4(m, 0x19191919u - u08 * 9u);
    unsigned u17 = shiftw(W0, W1, 1) | shiftw(W1, W2, 3);  // d=+-3, k=16
    m = vminu4(m, 0x19191919u - u17 * 16u);
    unsigned u26 = shiftw(W0, W1, 2) | shiftw(W1, W2, 2);  // d=+-2, k=21
    m = vminu4(m, 0x19191919u - u26 * 21u);
    unsigned u35 = shiftw(W0, W1, 3) | shiftw(W1, W2, 1);  // d=+-1, k=24
    m = vminu4(m, 0x19191919u - u35 * 24u);
    return m;
}

// ---------------------------------------------------------------------------
// Kernel 2: fully fused boundary loss. grid = 576 blocks x 256 threads.
// ---------------------------------------------------------------------------
__global__ __launch_bounds__(256) void boundary_fused(const float* __restrict__ pred,
                                                      const float* __restrict__ target,
                                                      float* __restrict__ acc,
                                                      float* __restrict__ out) {
    __shared__ unsigned fgm[NROWS * 10];   // fg mask bytes (0/1), 10 u32/row
    __shared__ unsigned bgm[NROWS * 10];   // valid-bg mask bytes (0/1)
    __shared__ unsigned swp[NROWS * 8];    // W-pass dist2 to bg, uchar4/u32
    __shared__ unsigned swn[NROWS * 8];    // W-pass dist2 to fg
    __shared__ float rsum[8];
    unsigned* whp = fgm;                   // W+H dist2 to bg (fgm dead by then)
    unsigned* whn = bgm;                   // W+H dist2 to fg

    const int tid = threadIdx.x;
    int x = blockIdx.x;
    const int wt = x % 3;  x /= 3;
    const int ht = x % 12; x /= 12;
    const int dt = x % 8;
    const int b  = x / 8;
    const int d0 = dt * DT, h0 = ht * HT, w0 = wt * WT;

    // ---- stage 1: mask -> packed bytes in LDS; 10 independent f4 loads/thread
    #pragma unroll
    for (int k = 0; k < 10; ++k) {
        const int idx = tid + 256 * k;               // [0, 2560)
        const int row = idx / 10;
        const int q   = idx - row * 10;
        const int dr = row >> 4, hr = row & 15;
        const int d = d0 - 4 + dr, h = h0 - 4 + hr;
        const int wb = w0 - 4 + 4 * q;               // float4-aligned
        unsigned fgw = 0u, bgw = 0u;
        if ((unsigned)d < DDIM && (unsigned)h < HDIM && (unsigned)wb < WDIM) {
            const float4 v = *(const float4*)(target +
                ((size_t)(b * DDIM + d) * HDIM + h) * WDIM + wb);
            fgw = (unsigned)(v.x > 0.5f)        | ((unsigned)(v.y > 0.5f) << 8) |
                  ((unsigned)(v.z > 0.5f) << 16) | ((unsigned)(v.w > 0.5f) << 24);
            bgw = fgw ^ 0x01010101u;
        }
        fgm[row * 10 + q] = fgw;
        bgm[row * 10 + q] = bgw;
    }
    __syncthreads();

    // ---- stage 2: W pass on byte masks -> packed capped dist2 ----
    {
        const int qp = tid & 7;                      // output quad (interior w)
        const int rb = tid >> 3;                     // 0..31
        #pragma unroll
        for (int k = 0; k < 8; ++k) {
            const int row  = rb + 32 * k;
            const int base = row * 10 + qp;          // window words qp..qp+2
            swn[row * 8 + qp] = wpass_quad(fgm[base], fgm[base + 1], fgm[base + 2]);
            swp[row * 8 + qp] = wpass_quad(bgm[base], bgm[base + 1], bgm[base + 2]);
        }
    }
    __syncthreads();

    // ---- stage 3: H pass, packed 9-tap min-plus (writes alias mask arrays) ----
    #pragma unroll
    for (int k = 0; k < 4; ++k) {
        const int g  = tid + 256 * k;                // (dr 0..15, hh 0..7, q 0..7)
        const int q  = g & 7;
        const int hh = (g >> 3) & 7;
        const int dr = g >> 6;
        unsigned p = 0x19191919u, n = 0x19191919u;
        #pragma unroll
        for (int t = 0; t < 9; ++t) {
            const unsigned add = (unsigned)((t - 4) * (t - 4)) * 0x01010101u;
            const int src = (dr * HH + hh + t) * 8 + q;
            p = vminu4(p, swp[src] + add);           // bytes <= 41 < 128: exact
            n = vminu4(n, swn[src] + add);
        }
        whp[(dr * HT + hh) * 8 + q] = p;
        whn[(dr * HT + hh) * 8 + q] = n;
    }
    __syncthreads();

    // ---- stage 4: D pass + loss on interior 8d x 8h x 32w ----
    float num = 0.f, den = 0.f;
    #pragma unroll
    for (int k = 0; k < 2; ++k) {
        const int g  = tid + 256 * k;                // (di 0..7, hh 0..7, q 0..7)
        const int q  = g & 7;
        const int hh = (g >> 3) & 7;
        const int di = g >> 6;
        unsigned p = 0x19191919u, n = 0x19191919u;
        #pragma unroll
        for (int t = 0; t < 9; ++t) {
            const unsigned add = (unsigned)((t - 4) * (t - 4)) * 0x01010101u;
            const int src = ((di + t) * HT + hh) * 8 + q;
            p = vminu4(p, whp[src] + add);
            n = vminu4(n, whn[src] + add);
        }
        const size_t gg = ((size_t)(b * DDIM + d0 + di) * HDIM + h0 + hh) * WDIM
                        + w0 + q * 4;
        const float4 pr = *(const float4*)(pred + gg);
        const float4 tg = *(const float4*)(target + gg);
        #pragma unroll
        for (int j = 0; j < 4; ++j) {
            const float pv = (float)((p >> (8 * j)) & 0xFFu);
            const float nv = (float)((n >> (8 * j)) & 0xFFu);
            const float prj = j == 0 ? pr.x : j == 1 ? pr.y : j == 2 ? pr.z : pr.w;
            const float tgj = j == 0 ? tg.x : j == 1 ? tg.y : j == 2 ? tg.z : tg.w;
            const float dp = sqrtf(pv);
            const float dn = sqrtf(nv);
            const float a  = fabsf(dn - dp);
            float w;
            if (a <= 3.0f)      w = 1.0f;
            else if (a >= 5.0f) w = 0.0f;
            else                w = 1.0f - (a - 3.0f) * 0.5f;
            const float lp  = fmaxf(logf(prj), -100.0f);
            const float l1  = fmaxf(logf(1.0f - prj), -100.0f);
            const float bce = -(tgj * lp + (1.0f - tgj) * l1);
            num += bce * w;
            den += w;
        }
    }

    // ---- wave reduce -> cross-wave LDS -> one atomic pair per block ----
    for (int off = 32; off > 0; off >>= 1) {
        num += __shfl_down(num, off);
        den += __shfl_down(den, off);
    }
    if ((tid & 63) == 0) {
        rsum[tid >> 6]       = num;
        rsum[4 + (tid >> 6)] = den;
    }
    __syncthreads();
    if (tid == 0) {
        float ns = rsum[0] + rsum[1] + rsum[2] + rsum[3];
        float ds = rsum[4] + rsum[5] + rsum[6] + rsum[7];
        atomicAdd(&acc[b], ns);
        atomicAdd(&acc[2 + b], ds);
        __threadfence();
        int done = atomicAdd((int*)acc + 4, 1);
        if (done == NBLK - 1) {                      // last block: finalize
            __threadfence();
            float n0  = atomicAdd(&acc[0], 0.0f);
            float n1  = atomicAdd(&acc[1], 0.0f);
            float d0_ = atomicAdd(&acc[2], 0.0f);
            float d1_ = atomicAdd(&acc[3], 0.0f);
            out[0] = 0.5f * (n0 / (d0_ + 1e-5f) + n1 / (d1_ + 1e-5f));
        }
    }
}

extern "C" void kernel_launch(void* const* d_in, const int* in_sizes, int n_in,
                              void* d_out, int out_size, void* d_ws, size_t ws_size,
                              hipStream_t stream) {
    const float* pred   = (const float*)d_in[0];
    const float* target = (const float*)d_in[1];
    float* acc = (float*)d_ws;          // 4 floats num/den + 1 int counter
    float* out = (float*)d_out;

    init_acc<<<1, 64, 0, stream>>>(acc);
    boundary_fused<<<NBLK, 256, 0, stream>>>(pred, target, acc, out);
}